// Round 1
// baseline (220.048 us; speedup 1.0000x reference)
//
#include <hip/hip_runtime.h>

#define NB 16384
#define TT 10
#define DIN 256
#define HH 16
#define NG 64      // 4*H
#define NF 160     // T*H

__device__ __forceinline__ float sig_(float x) {
    return 1.0f / (1.0f + __expf(-x));
}
__device__ __forceinline__ float tanh_(float x) {
    x = fminf(fmaxf(x, -15.0f), 15.0f);   // avoid inf/inf NaN
    float e = __expf(2.0f * x);
    return (e - 1.0f) / (e + 1.0f);
}

// K1: xg0[row=b*T+t][g] = x[row,:] . w_ih0[g,:] + b_ih0[g] + b_hh0[g]
// Tiled fp32 GEMM: 64x64 tile per block (256 thr), 4x4 per-thread tile.
__global__ __launch_bounds__(256) void k_proj(
        const float* __restrict__ x, const float* __restrict__ w,
        const float* __restrict__ bi, const float* __restrict__ bh,
        float* __restrict__ xg) {
    __shared__ float aT[64][68];  // [k][m], stride 68 floats: 16B-aligned rows, odd/4 bank spread
    __shared__ float bT[64][68];  // [k][n]
    const int tid = threadIdx.x;
    const int row0 = blockIdx.x * 64;
    const int tm = tid >> 4;   // 0..15
    const int tn = tid & 15;   // 0..15

    float acc[4][4];
    #pragma unroll
    for (int i = 0; i < 4; ++i)
        #pragma unroll
        for (int j = 0; j < 4; ++j) acc[i][j] = 0.0f;

    const int cs = (tid & 15) * 4;  // staging: col within k-chunk
    const int rb = tid >> 4;        // staging: row base (0..15)

    for (int kc = 0; kc < 4; ++kc) {
        #pragma unroll
        for (int i = 0; i < 4; ++i) {
            const int r = rb + i * 16;  // 0..63
            float4 av = *(const float4*)(x + (size_t)(row0 + r) * DIN + kc * 64 + cs);
            aT[cs + 0][r] = av.x; aT[cs + 1][r] = av.y;
            aT[cs + 2][r] = av.z; aT[cs + 3][r] = av.w;
            float4 bv = *(const float4*)(w + (size_t)r * DIN + kc * 64 + cs);
            bT[cs + 0][r] = bv.x; bT[cs + 1][r] = bv.y;
            bT[cs + 2][r] = bv.z; bT[cs + 3][r] = bv.w;
        }
        __syncthreads();
        #pragma unroll 8
        for (int k = 0; k < 64; ++k) {
            float4 a4 = *(const float4*)&aT[k][tm * 4];
            float4 b4 = *(const float4*)&bT[k][tn * 4];
            acc[0][0] += a4.x * b4.x; acc[0][1] += a4.x * b4.y;
            acc[0][2] += a4.x * b4.z; acc[0][3] += a4.x * b4.w;
            acc[1][0] += a4.y * b4.x; acc[1][1] += a4.y * b4.y;
            acc[1][2] += a4.y * b4.z; acc[1][3] += a4.y * b4.w;
            acc[2][0] += a4.z * b4.x; acc[2][1] += a4.z * b4.y;
            acc[2][2] += a4.z * b4.z; acc[2][3] += a4.z * b4.w;
            acc[3][0] += a4.w * b4.x; acc[3][1] += a4.w * b4.y;
            acc[3][2] += a4.w * b4.z; acc[3][3] += a4.w * b4.w;
        }
        __syncthreads();
    }
    const int col = tn * 4;
    float4 bi4 = *(const float4*)(bi + col);
    float4 bh4 = *(const float4*)(bh + col);
    const float bx = bi4.x + bh4.x, by = bi4.y + bh4.y;
    const float bz = bi4.z + bh4.z, bw = bi4.w + bh4.w;
    #pragma unroll
    for (int i = 0; i < 4; ++i) {
        const int row = row0 + tm * 4 + i;
        float4 o;
        o.x = acc[i][0] + bx; o.y = acc[i][1] + by;
        o.z = acc[i][2] + bz; o.w = acc[i][3] + bw;
        *(float4*)(xg + (size_t)row * NG + col) = o;
    }
}

// K2: fused 2-layer LSTM recurrence. One wave per sample; lane = gate index.
// Torch gate order across lanes: 0-15 i, 16-31 f, 32-47 g(tanh), 48-63 o.
// Lane holds h[lane&15] redundantly; cross-lane via shuffles.
__global__ __launch_bounds__(256) void k_lstm(
        const float* __restrict__ xg, const float* __restrict__ whh0,
        const float* __restrict__ wih1, const float* __restrict__ whh1,
        const float* __restrict__ bi1, const float* __restrict__ bh1,
        float* __restrict__ flat) {
    const int lane = threadIdx.x & 63;
    const int b = blockIdx.x * 4 + (threadIdx.x >> 6);
    const int g = lane;

    float w0[16], w1[16], w2[16];
    #pragma unroll
    for (int q = 0; q < 4; ++q) {
        float4 v0 = *(const float4*)(whh0 + g * HH + q * 4);
        w0[q*4+0] = v0.x; w0[q*4+1] = v0.y; w0[q*4+2] = v0.z; w0[q*4+3] = v0.w;
        float4 v1 = *(const float4*)(wih1 + g * HH + q * 4);
        w1[q*4+0] = v1.x; w1[q*4+1] = v1.y; w1[q*4+2] = v1.z; w1[q*4+3] = v1.w;
        float4 v2 = *(const float4*)(whh1 + g * HH + q * 4);
        w2[q*4+0] = v2.x; w2[q*4+1] = v2.y; w2[q*4+2] = v2.z; w2[q*4+3] = v2.w;
    }
    const float bias1 = bi1[g] + bh1[g];
    const bool isg = (g & 48) == 32;  // candidate gate -> tanh
    float h0 = 0.0f, c0 = 0.0f, h1 = 0.0f, c1 = 0.0f;
    const float* xgb = xg + (size_t)b * TT * NG;

    for (int t = 0; t < TT; ++t) {
        float gate = xgb[t * NG + g];
        #pragma unroll
        for (int j = 0; j < 16; ++j) gate += __shfl(h0, j, 64) * w0[j];
        float a = isg ? tanh_(gate) : sig_(gate);
        float iv = __shfl(a, (g & 15), 64);
        float fv = __shfl(a, (g & 15) + 16, 64);
        float gv = __shfl(a, (g & 15) + 32, 64);
        float ov = __shfl(a, (g & 15) + 48, 64);
        c0 = fv * c0 + iv * gv;
        h0 = ov * tanh_(c0);

        float gate1 = bias1;
        #pragma unroll
        for (int j = 0; j < 16; ++j) gate1 += __shfl(h0, j, 64) * w1[j];
        #pragma unroll
        for (int j = 0; j < 16; ++j) gate1 += __shfl(h1, j, 64) * w2[j];
        float a1 = isg ? tanh_(gate1) : sig_(gate1);
        iv = __shfl(a1, (g & 15), 64);
        fv = __shfl(a1, (g & 15) + 16, 64);
        gv = __shfl(a1, (g & 15) + 32, 64);
        ov = __shfl(a1, (g & 15) + 48, 64);
        c1 = fv * c1 + iv * gv;
        h1 = ov * tanh_(c1);

        if (g < HH) flat[(size_t)b * NF + t * HH + g] = h1;
    }
}

// K3: batch-norm statistics (training mode, biased var), fused to scale/shift.
// One block per feature; deterministic tree reduction (no float atomics).
__global__ __launch_bounds__(256) void k_bnstats(
        const float* __restrict__ flat, const float* __restrict__ gamma,
        const float* __restrict__ beta, float* __restrict__ scale,
        float* __restrict__ shift) {
    const int f = blockIdx.x;
    const int tid = threadIdx.x;
    float s = 0.0f, s2 = 0.0f;
    for (int i = tid; i < NB; i += 256) {
        float v = flat[(size_t)i * NF + f];
        s += v; s2 += v * v;
    }
    #pragma unroll
    for (int o = 32; o > 0; o >>= 1) {
        s  += __shfl_down(s, o, 64);
        s2 += __shfl_down(s2, o, 64);
    }
    __shared__ float rs[4], rq[4];
    const int wv = tid >> 6;
    if ((tid & 63) == 0) { rs[wv] = s; rq[wv] = s2; }
    __syncthreads();
    if (tid == 0) {
        float S = rs[0] + rs[1] + rs[2] + rs[3];
        float Q = rq[0] + rq[1] + rq[2] + rq[3];
        float mean = S * (1.0f / NB);
        float var = Q * (1.0f / NB) - mean * mean;
        float sc = gamma[f] * rsqrtf(var + 1e-5f);
        scale[f] = sc;
        shift[f] = beta[f] - mean * sc;
    }
}

// K4: BN-apply + LeakyReLU + concat(agegender) + FC(162->2) + softmax.
// One wave per sample; features strided across lanes, shuffle reduce.
__global__ __launch_bounds__(256) void k_fc(
        const float* __restrict__ flat, const float* __restrict__ scale,
        const float* __restrict__ shift, const float* __restrict__ ag,
        const float* __restrict__ fcw, const float* __restrict__ fcb,
        float* __restrict__ out) {
    const int lane = threadIdx.x & 63;
    const int b = blockIdx.x * 4 + (threadIdx.x >> 6);
    const float* fr = flat + (size_t)b * NF;
    float p0 = 0.0f, p1 = 0.0f;
    for (int f = lane; f < NF; f += 64) {
        float xn = fr[f] * scale[f] + shift[f];
        float a = xn >= 0.0f ? xn : 0.01f * xn;
        p0 += a * fcw[f];
        p1 += a * fcw[162 + f];
    }
    #pragma unroll
    for (int o = 32; o > 0; o >>= 1) {
        p0 += __shfl_down(p0, o, 64);
        p1 += __shfl_down(p1, o, 64);
    }
    if (lane == 0) {
        float a0 = ag[(size_t)b * 2 + 0], a1 = ag[(size_t)b * 2 + 1];
        float l0 = p0 + a0 * fcw[160] + a1 * fcw[161] + fcb[0];
        float l1 = p1 + a0 * fcw[162 + 160] + a1 * fcw[162 + 161] + fcb[1];
        float m = fmaxf(l0, l1);
        float e0 = __expf(l0 - m), e1 = __expf(l1 - m);
        float inv = 1.0f / (e0 + e1);
        out[(size_t)b * 2 + 0] = e0 * inv;
        out[(size_t)b * 2 + 1] = e1 * inv;
    }
}

extern "C" void kernel_launch(void* const* d_in, const int* in_sizes, int n_in,
                              void* d_out, int out_size, void* d_ws, size_t ws_size,
                              hipStream_t stream) {
    const float* x     = (const float*)d_in[0];   // [16384,10,256]
    const float* ag    = (const float*)d_in[1];   // [16384,2]
    const float* wih0  = (const float*)d_in[2];   // [64,256]
    const float* whh0  = (const float*)d_in[3];   // [64,16]
    const float* bih0  = (const float*)d_in[4];   // [64]
    const float* bhh0  = (const float*)d_in[5];   // [64]
    const float* wih1  = (const float*)d_in[6];   // [64,16]
    const float* whh1  = (const float*)d_in[7];   // [64,16]
    const float* bih1  = (const float*)d_in[8];   // [64]
    const float* bhh1  = (const float*)d_in[9];   // [64]
    const float* gamma = (const float*)d_in[10];  // [160]
    const float* beta  = (const float*)d_in[11];  // [160]
    const float* fcw   = (const float*)d_in[12];  // [2,162]
    const float* fcb   = (const float*)d_in[13];  // [2]
    float* out = (float*)d_out;                   // [16384,2]

    float* ws = (float*)d_ws;
    float* xg0   = ws;                       // 16384*10*64 = 10,485,760 floats
    float* flat  = ws + 10485760;            // 16384*160   =  2,621,440 floats
    float* scale = ws + 13107200;            // 160
    float* shift = ws + 13107360;            // 160

    k_proj<<<dim3(2560), dim3(256), 0, stream>>>(x, wih0, bih0, bhh0, xg0);
    k_lstm<<<dim3(4096), dim3(256), 0, stream>>>(xg0, whh0, wih1, whh1, bih1, bhh1, flat);
    k_bnstats<<<dim3(160), dim3(256), 0, stream>>>(flat, gamma, beta, scale, shift);
    k_fc<<<dim3(4096), dim3(256), 0, stream>>>(flat, scale, shift, ag, fcw, fcb, out);
}

// Round 2
// 157.734 us; speedup vs baseline: 1.3951x; 1.3951x over previous
//
#include <hip/hip_runtime.h>

#define NB 16384
#define TT 10
#define DIN 256
#define HH 16
#define NG 64      // 4*H
#define NF 160     // T*H

__device__ __forceinline__ float sig_(float x) {
    return 1.0f / (1.0f + __expf(-x));
}
__device__ __forceinline__ float tanh_(float x) {
    x = fminf(fmaxf(x, -15.0f), 15.0f);   // avoid inf/inf NaN
    float e = __expf(2.0f * x);
    return (e - 1.0f) / (e + 1.0f);
}
// SGPR broadcast of lane `l` (compile-time constant) — pure VALU, no LDS pipe.
__device__ __forceinline__ float rl_(float v, int l) {
    return __int_as_float(__builtin_amdgcn_readlane(__float_as_int(v), l));
}

// K1: xg0[row=b*T+t][g] = x[row,:] . w_ih0[g,:] + b_ih0[g] + b_hh0[g]
// Tiled fp32 GEMM: 64x64 tile per block (256 thr), 4x4 per-thread tile.
__global__ __launch_bounds__(256) void k_proj(
        const float* __restrict__ x, const float* __restrict__ w,
        const float* __restrict__ bi, const float* __restrict__ bh,
        float* __restrict__ xg) {
    __shared__ float aT[64][68];
    __shared__ float bT[64][68];
    const int tid = threadIdx.x;
    const int row0 = blockIdx.x * 64;
    const int tm = tid >> 4;   // 0..15
    const int tn = tid & 15;   // 0..15

    float acc[4][4];
    #pragma unroll
    for (int i = 0; i < 4; ++i)
        #pragma unroll
        for (int j = 0; j < 4; ++j) acc[i][j] = 0.0f;

    const int cs = (tid & 15) * 4;
    const int rb = tid >> 4;

    for (int kc = 0; kc < 4; ++kc) {
        #pragma unroll
        for (int i = 0; i < 4; ++i) {
            const int r = rb + i * 16;
            float4 av = *(const float4*)(x + (size_t)(row0 + r) * DIN + kc * 64 + cs);
            aT[cs + 0][r] = av.x; aT[cs + 1][r] = av.y;
            aT[cs + 2][r] = av.z; aT[cs + 3][r] = av.w;
            float4 bv = *(const float4*)(w + (size_t)r * DIN + kc * 64 + cs);
            bT[cs + 0][r] = bv.x; bT[cs + 1][r] = bv.y;
            bT[cs + 2][r] = bv.z; bT[cs + 3][r] = bv.w;
        }
        __syncthreads();
        #pragma unroll 8
        for (int k = 0; k < 64; ++k) {
            float4 a4 = *(const float4*)&aT[k][tm * 4];
            float4 b4 = *(const float4*)&bT[k][tn * 4];
            acc[0][0] += a4.x * b4.x; acc[0][1] += a4.x * b4.y;
            acc[0][2] += a4.x * b4.z; acc[0][3] += a4.x * b4.w;
            acc[1][0] += a4.y * b4.x; acc[1][1] += a4.y * b4.y;
            acc[1][2] += a4.y * b4.z; acc[1][3] += a4.y * b4.w;
            acc[2][0] += a4.z * b4.x; acc[2][1] += a4.z * b4.y;
            acc[2][2] += a4.z * b4.z; acc[2][3] += a4.z * b4.w;
            acc[3][0] += a4.w * b4.x; acc[3][1] += a4.w * b4.y;
            acc[3][2] += a4.w * b4.z; acc[3][3] += a4.w * b4.w;
        }
        __syncthreads();
    }
    const int col = tn * 4;
    float4 bi4 = *(const float4*)(bi + col);
    float4 bh4 = *(const float4*)(bh + col);
    const float bx = bi4.x + bh4.x, by = bi4.y + bh4.y;
    const float bz = bi4.z + bh4.z, bw = bi4.w + bh4.w;
    #pragma unroll
    for (int i = 0; i < 4; ++i) {
        const int row = row0 + tm * 4 + i;
        float4 o;
        o.x = acc[i][0] + bx; o.y = acc[i][1] + by;
        o.z = acc[i][2] + bz; o.w = acc[i][3] + bw;
        *(float4*)(xg + (size_t)row * NG + col) = o;
    }
}

// K2: fused 2-layer LSTM recurrence. One wave per sample; lane = gate index g.
// Torch gate order: lanes 0-15 i, 16-31 f, 32-47 g(tanh), 48-63 o. j = g&15.
// State h/c lives ONLY on lanes 0-15 (lane j owns h[j],c[j]); broadcasts of h
// use v_readlane (SGPR, VALU-only). Post-activation gather: 3 shfl_down.
__global__ __launch_bounds__(256) void k_lstm(
        const float* __restrict__ xg, const float* __restrict__ whh0,
        const float* __restrict__ wih1, const float* __restrict__ whh1,
        const float* __restrict__ bi1, const float* __restrict__ bh1,
        float* __restrict__ flat) {
    const int lane = threadIdx.x & 63;
    const int b = blockIdx.x * 4 + (threadIdx.x >> 6);
    const int g = lane;

    float w0[16], w1[16], w2[16];
    #pragma unroll
    for (int q = 0; q < 4; ++q) {
        float4 v0 = *(const float4*)(whh0 + g * HH + q * 4);
        w0[q*4+0] = v0.x; w0[q*4+1] = v0.y; w0[q*4+2] = v0.z; w0[q*4+3] = v0.w;
        float4 v1 = *(const float4*)(wih1 + g * HH + q * 4);
        w1[q*4+0] = v1.x; w1[q*4+1] = v1.y; w1[q*4+2] = v1.z; w1[q*4+3] = v1.w;
        float4 v2 = *(const float4*)(whh1 + g * HH + q * 4);
        w2[q*4+0] = v2.x; w2[q*4+1] = v2.y; w2[q*4+2] = v2.z; w2[q*4+3] = v2.w;
    }
    const float bias1 = bi1[g] + bh1[g];
    const bool isg = (g & 48) == 32;  // candidate gate -> tanh
    float h0 = 0.0f, c0 = 0.0f, h1 = 0.0f, c1 = 0.0f;
    const float* xgb = xg + (size_t)b * TT * NG;

    for (int t = 0; t < TT; ++t) {
        // ---- layer 0 gates: xg + Whh0 . h0 (h0 valid on lanes 0-15) ----
        float s0 = xgb[t * NG + g], s1 = 0.0f, s2 = 0.0f, s3 = 0.0f;
        #pragma unroll
        for (int q = 0; q < 4; ++q) {
            s0 += rl_(h0, 4*q + 0) * w0[4*q + 0];
            s1 += rl_(h0, 4*q + 1) * w0[4*q + 1];
            s2 += rl_(h0, 4*q + 2) * w0[4*q + 2];
            s3 += rl_(h0, 4*q + 3) * w0[4*q + 3];
        }
        float gate = (s0 + s1) + (s2 + s3);
        float a = isg ? tanh_(gate) : sig_(gate);
        // gather f/g/o activations down to lanes 0-15 (i is local there)
        float af = __shfl_down(a, 16, 64);
        float ac = __shfl_down(a, 32, 64);
        float ao = __shfl_down(a, 48, 64);
        c0 = af * c0 + a * ac;        // valid on lanes 0-15 only
        h0 = ao * tanh_(c0);

        // ---- layer 1 gates: bias + Wih1 . h0 + Whh1 . h1 ----
        float u0 = bias1, u1 = 0.0f, u2 = 0.0f, u3 = 0.0f;
        float v0 = 0.0f, v1 = 0.0f, v2 = 0.0f, v3 = 0.0f;
        #pragma unroll
        for (int q = 0; q < 4; ++q) {
            u0 += rl_(h0, 4*q + 0) * w1[4*q + 0];
            u1 += rl_(h0, 4*q + 1) * w1[4*q + 1];
            u2 += rl_(h0, 4*q + 2) * w1[4*q + 2];
            u3 += rl_(h0, 4*q + 3) * w1[4*q + 3];
            v0 += rl_(h1, 4*q + 0) * w2[4*q + 0];
            v1 += rl_(h1, 4*q + 1) * w2[4*q + 1];
            v2 += rl_(h1, 4*q + 2) * w2[4*q + 2];
            v3 += rl_(h1, 4*q + 3) * w2[4*q + 3];
        }
        float gate1 = ((u0 + v0) + (u1 + v1)) + ((u2 + v2) + (u3 + v3));
        float a1 = isg ? tanh_(gate1) : sig_(gate1);
        af = __shfl_down(a1, 16, 64);
        ac = __shfl_down(a1, 32, 64);
        ao = __shfl_down(a1, 48, 64);
        c1 = af * c1 + a1 * ac;
        h1 = ao * tanh_(c1);

        if (g < HH) flat[(size_t)b * NF + t * HH + g] = h1;
    }
}

// K3a: per-chunk partial sums for BN stats, coalesced reads.
// 256 blocks x 192 thr; block p covers rows [p*64, p*64+64); thread f < 160.
__global__ __launch_bounds__(192) void k_bnA(
        const float* __restrict__ flat, float* __restrict__ psum,
        float* __restrict__ psq) {
    const int f = threadIdx.x;
    if (f >= NF) return;
    const int p = blockIdx.x;
    const float* base = flat + (size_t)p * 64 * NF + f;
    float s0 = 0.0f, s1 = 0.0f, q0 = 0.0f, q1 = 0.0f;
    #pragma unroll 4
    for (int r = 0; r < 64; r += 2) {
        float a = base[(size_t)r * NF];
        float b2 = base[(size_t)(r + 1) * NF];
        s0 += a; q0 += a * a;
        s1 += b2; q1 += b2 * b2;
    }
    psum[p * NF + f] = s0 + s1;
    psq[p * NF + f] = q0 + q1;
}

// K3b: reduce 256 partials per feature -> fused scale/shift.
__global__ __launch_bounds__(256) void k_bnB(
        const float* __restrict__ psum, const float* __restrict__ psq,
        const float* __restrict__ gamma, const float* __restrict__ beta,
        float* __restrict__ scale, float* __restrict__ shift) {
    const int f = blockIdx.x;
    const int p = threadIdx.x;
    float s = psum[p * NF + f];
    float q = psq[p * NF + f];
    #pragma unroll
    for (int o = 32; o > 0; o >>= 1) {
        s += __shfl_down(s, o, 64);
        q += __shfl_down(q, o, 64);
    }
    __shared__ float rs[4], rq[4];
    const int wv = p >> 6;
    if ((p & 63) == 0) { rs[wv] = s; rq[wv] = q; }
    __syncthreads();
    if (p == 0) {
        float S = rs[0] + rs[1] + rs[2] + rs[3];
        float Q = rq[0] + rq[1] + rq[2] + rq[3];
        float mean = S * (1.0f / NB);
        float var = Q * (1.0f / NB) - mean * mean;
        float sc = gamma[f] * rsqrtf(var + 1e-5f);
        scale[f] = sc;
        shift[f] = beta[f] - mean * sc;
    }
}

// K4: BN-apply + LeakyReLU + concat(agegender) + FC(162->2) + softmax.
__global__ __launch_bounds__(256) void k_fc(
        const float* __restrict__ flat, const float* __restrict__ scale,
        const float* __restrict__ shift, const float* __restrict__ ag,
        const float* __restrict__ fcw, const float* __restrict__ fcb,
        float* __restrict__ out) {
    const int lane = threadIdx.x & 63;
    const int b = blockIdx.x * 4 + (threadIdx.x >> 6);
    const float* fr = flat + (size_t)b * NF;
    float p0 = 0.0f, p1 = 0.0f;
    for (int f = lane; f < NF; f += 64) {
        float xn = fr[f] * scale[f] + shift[f];
        float a = xn >= 0.0f ? xn : 0.01f * xn;
        p0 += a * fcw[f];
        p1 += a * fcw[162 + f];
    }
    #pragma unroll
    for (int o = 32; o > 0; o >>= 1) {
        p0 += __shfl_down(p0, o, 64);
        p1 += __shfl_down(p1, o, 64);
    }
    if (lane == 0) {
        float a0 = ag[(size_t)b * 2 + 0], a1 = ag[(size_t)b * 2 + 1];
        float l0 = p0 + a0 * fcw[160] + a1 * fcw[161] + fcb[0];
        float l1 = p1 + a0 * fcw[162 + 160] + a1 * fcw[162 + 161] + fcb[1];
        float m = fmaxf(l0, l1);
        float e0 = __expf(l0 - m), e1 = __expf(l1 - m);
        float inv = 1.0f / (e0 + e1);
        out[(size_t)b * 2 + 0] = e0 * inv;
        out[(size_t)b * 2 + 1] = e1 * inv;
    }
}

extern "C" void kernel_launch(void* const* d_in, const int* in_sizes, int n_in,
                              void* d_out, int out_size, void* d_ws, size_t ws_size,
                              hipStream_t stream) {
    const float* x     = (const float*)d_in[0];
    const float* ag    = (const float*)d_in[1];
    const float* wih0  = (const float*)d_in[2];
    const float* whh0  = (const float*)d_in[3];
    const float* bih0  = (const float*)d_in[4];
    const float* bhh0  = (const float*)d_in[5];
    const float* wih1  = (const float*)d_in[6];
    const float* whh1  = (const float*)d_in[7];
    const float* bih1  = (const float*)d_in[8];
    const float* bhh1  = (const float*)d_in[9];
    const float* gamma = (const float*)d_in[10];
    const float* beta  = (const float*)d_in[11];
    const float* fcw   = (const float*)d_in[12];
    const float* fcb   = (const float*)d_in[13];
    float* out = (float*)d_out;

    float* ws = (float*)d_ws;
    float* xg0   = ws;                       // 10,485,760 floats
    float* flat  = ws + 10485760;            //  2,621,440 floats
    float* psum  = ws + 13107200;            //     40,960 floats (256*160)
    float* psq   = ws + 13148160;            //     40,960 floats
    float* scale = ws + 13189120;            //        160
    float* shift = ws + 13189280;            //        160

    k_proj<<<dim3(2560), dim3(256), 0, stream>>>(x, wih0, bih0, bhh0, xg0);
    k_lstm<<<dim3(4096), dim3(256), 0, stream>>>(xg0, whh0, wih1, whh1, bih1, bhh1, flat);
    k_bnA<<<dim3(256), dim3(192), 0, stream>>>(flat, psum, psq);
    k_bnB<<<dim3(160), dim3(256), 0, stream>>>(psum, psq, gamma, beta, scale, shift);
    k_fc<<<dim3(4096), dim3(256), 0, stream>>>(flat, scale, shift, ag, fcw, fcb, out);
}

// Round 3
// 116.046 us; speedup vs baseline: 1.8962x; 1.3592x over previous
//
#include <hip/hip_runtime.h>

#define NB 16384
#define TT 10
#define DIN 256
#define HH 16
#define NG 64      // 4*H
#define NF 160     // T*H

typedef __attribute__((ext_vector_type(8))) _Float16 half8;
typedef __attribute__((ext_vector_type(4))) float f32x4;

__device__ __forceinline__ float sig_(float x) {
    return 1.0f / (1.0f + __expf(-x));
}
__device__ __forceinline__ float tanh_(float x) {
    x = fminf(fmaxf(x, -15.0f), 15.0f);
    float e = __expf(2.0f * x);
    return (e - 1.0f) / (e + 1.0f);
}
__device__ __forceinline__ float rl_(float v, int l) {
    return __int_as_float(__builtin_amdgcn_readlane(__float_as_int(v), l));
}

// K1: xg0[row][g] = x[row,:] . w_ih0[g,:] + b_ih0[g] + b_hh0[g]  via f16 MFMA.
// x split into hi+lo fp16 (2 MFMAs), w single fp16 (error ~2^-11, safe).
// Fragment convention (consistent for A and B, so any k-permutation is valid):
//   lane l -> row/col (l&15), k = s*32 + (l>>4)*8 + j, j=0..7.
// C/D (verified m89): col = lane&15, row = (lane>>4)*4 + reg.
// Block: 256 thr = 4 waves; wave does 32 rows x 64 cols; block 128 rows.
__global__ __launch_bounds__(256) void k_proj(
        const float* __restrict__ x, const float* __restrict__ w,
        const float* __restrict__ bi, const float* __restrict__ bh,
        float* __restrict__ xg) {
    __shared__ half8 Blds[2048];   // [c][s][lane] fragments, 32 KB
    __shared__ float bsum[NG];
    const int tid = threadIdx.x;
    const int l = tid & 63;
    const int wv = tid >> 6;

    // --- stage B: convert w (fp32) into fragment-ordered fp16 LDS, once ---
    for (int fi = tid; fi < 2048; fi += 256) {
        const int c = fi >> 9;          // col-tile 0..3
        const int s = (fi >> 6) & 7;    // k-step 0..7
        const int ll = fi & 63;
        const int row = c * 16 + (ll & 15);
        const int k0 = s * 32 + ((ll >> 4) << 3);
        const float* wp = w + (size_t)row * DIN + k0;
        float4 a = *(const float4*)wp;
        float4 b = *(const float4*)(wp + 4);
        half8 h;
        h[0] = (_Float16)a.x; h[1] = (_Float16)a.y;
        h[2] = (_Float16)a.z; h[3] = (_Float16)a.w;
        h[4] = (_Float16)b.x; h[5] = (_Float16)b.y;
        h[6] = (_Float16)b.z; h[7] = (_Float16)b.w;
        Blds[fi] = h;
    }
    if (tid < NG) bsum[tid] = bi[tid] + bh[tid];
    __syncthreads();

    const int row0 = blockIdx.x * 128 + wv * 32;
    const int rowA0 = row0 + (l & 15);
    const int kb = (l >> 4) << 3;

    f32x4 acc[2][4];
    #pragma unroll
    for (int m = 0; m < 2; ++m)
        #pragma unroll
        for (int c = 0; c < 4; ++c) acc[m][c] = (f32x4)0.0f;

    #pragma unroll
    for (int s = 0; s < 8; ++s) {
        const int k0 = s * 32 + kb;
        half8 ah[2], al[2];
        #pragma unroll
        for (int m = 0; m < 2; ++m) {
            const float* xp = x + (size_t)(rowA0 + m * 16) * DIN + k0;
            float4 a = *(const float4*)xp;
            float4 b = *(const float4*)(xp + 4);
            float f[8] = {a.x, a.y, a.z, a.w, b.x, b.y, b.z, b.w};
            #pragma unroll
            for (int j = 0; j < 8; ++j) {
                _Float16 hi = (_Float16)f[j];
                ah[m][j] = hi;
                al[m][j] = (_Float16)(f[j] - (float)hi);
            }
        }
        #pragma unroll
        for (int c = 0; c < 4; ++c) {
            half8 bf = Blds[(c * 8 + s) * 64 + l];
            #pragma unroll
            for (int m = 0; m < 2; ++m) {
                acc[m][c] = __builtin_amdgcn_mfma_f32_16x16x32_f16(ah[m], bf, acc[m][c], 0, 0, 0);
                acc[m][c] = __builtin_amdgcn_mfma_f32_16x16x32_f16(al[m], bf, acc[m][c], 0, 0, 0);
            }
        }
    }

    // epilogue: add bias, store (lanes 0-15 -> consecutive cols, coalesced)
    #pragma unroll
    for (int m = 0; m < 2; ++m) {
        const int rbase = row0 + m * 16 + ((l >> 4) << 2);
        #pragma unroll
        for (int c = 0; c < 4; ++c) {
            const int col = c * 16 + (l & 15);
            const float bb = bsum[col];
            #pragma unroll
            for (int r = 0; r < 4; ++r)
                xg[(size_t)(rbase + r) * NG + col] = acc[m][c][r] + bb;
        }
    }
}

// K2: fused 2-layer LSTM recurrence (readlane broadcasts, state on lanes 0-15).
__global__ __launch_bounds__(256) void k_lstm(
        const float* __restrict__ xg, const float* __restrict__ whh0,
        const float* __restrict__ wih1, const float* __restrict__ whh1,
        const float* __restrict__ bi1, const float* __restrict__ bh1,
        float* __restrict__ flat) {
    const int lane = threadIdx.x & 63;
    const int b = blockIdx.x * 4 + (threadIdx.x >> 6);
    const int g = lane;

    float w0[16], w1[16], w2[16];
    #pragma unroll
    for (int q = 0; q < 4; ++q) {
        float4 v0 = *(const float4*)(whh0 + g * HH + q * 4);
        w0[q*4+0] = v0.x; w0[q*4+1] = v0.y; w0[q*4+2] = v0.z; w0[q*4+3] = v0.w;
        float4 v1 = *(const float4*)(wih1 + g * HH + q * 4);
        w1[q*4+0] = v1.x; w1[q*4+1] = v1.y; w1[q*4+2] = v1.z; w1[q*4+3] = v1.w;
        float4 v2 = *(const float4*)(whh1 + g * HH + q * 4);
        w2[q*4+0] = v2.x; w2[q*4+1] = v2.y; w2[q*4+2] = v2.z; w2[q*4+3] = v2.w;
    }
    const float bias1 = bi1[g] + bh1[g];
    const bool isg = (g & 48) == 32;
    float h0 = 0.0f, c0 = 0.0f, h1 = 0.0f, c1 = 0.0f;
    const float* xgb = xg + (size_t)b * TT * NG;

    for (int t = 0; t < TT; ++t) {
        float s0 = xgb[t * NG + g], s1 = 0.0f, s2 = 0.0f, s3 = 0.0f;
        #pragma unroll
        for (int q = 0; q < 4; ++q) {
            s0 += rl_(h0, 4*q + 0) * w0[4*q + 0];
            s1 += rl_(h0, 4*q + 1) * w0[4*q + 1];
            s2 += rl_(h0, 4*q + 2) * w0[4*q + 2];
            s3 += rl_(h0, 4*q + 3) * w0[4*q + 3];
        }
        float gate = (s0 + s1) + (s2 + s3);
        float a = isg ? tanh_(gate) : sig_(gate);
        float af = __shfl_down(a, 16, 64);
        float ac = __shfl_down(a, 32, 64);
        float ao = __shfl_down(a, 48, 64);
        c0 = af * c0 + a * ac;
        h0 = ao * tanh_(c0);

        float u0 = bias1, u1 = 0.0f, u2 = 0.0f, u3 = 0.0f;
        float v0 = 0.0f, v1 = 0.0f, v2 = 0.0f, v3 = 0.0f;
        #pragma unroll
        for (int q = 0; q < 4; ++q) {
            u0 += rl_(h0, 4*q + 0) * w1[4*q + 0];
            u1 += rl_(h0, 4*q + 1) * w1[4*q + 1];
            u2 += rl_(h0, 4*q + 2) * w1[4*q + 2];
            u3 += rl_(h0, 4*q + 3) * w1[4*q + 3];
            v0 += rl_(h1, 4*q + 0) * w2[4*q + 0];
            v1 += rl_(h1, 4*q + 1) * w2[4*q + 1];
            v2 += rl_(h1, 4*q + 2) * w2[4*q + 2];
            v3 += rl_(h1, 4*q + 3) * w2[4*q + 3];
        }
        float gate1 = ((u0 + v0) + (u1 + v1)) + ((u2 + v2) + (u3 + v3));
        float a1 = isg ? tanh_(gate1) : sig_(gate1);
        af = __shfl_down(a1, 16, 64);
        ac = __shfl_down(a1, 32, 64);
        ao = __shfl_down(a1, 48, 64);
        c1 = af * c1 + a1 * ac;
        h1 = ao * tanh_(c1);

        if (g < HH) flat[(size_t)b * NF + t * HH + g] = h1;
    }
}

// K3a: per-chunk partial sums for BN stats, coalesced reads.
__global__ __launch_bounds__(192) void k_bnA(
        const float* __restrict__ flat, float* __restrict__ psum,
        float* __restrict__ psq) {
    const int f = threadIdx.x;
    if (f >= NF) return;
    const int p = blockIdx.x;
    const float* base = flat + (size_t)p * 64 * NF + f;
    float s0 = 0.0f, s1 = 0.0f, q0 = 0.0f, q1 = 0.0f;
    #pragma unroll 4
    for (int r = 0; r < 64; r += 2) {
        float a = base[(size_t)r * NF];
        float b2 = base[(size_t)(r + 1) * NF];
        s0 += a; q0 += a * a;
        s1 += b2; q1 += b2 * b2;
    }
    psum[p * NF + f] = s0 + s1;
    psq[p * NF + f] = q0 + q1;
}

// K3b: reduce partials -> fused scale/shift.
__global__ __launch_bounds__(256) void k_bnB(
        const float* __restrict__ psum, const float* __restrict__ psq,
        const float* __restrict__ gamma, const float* __restrict__ beta,
        float* __restrict__ scale, float* __restrict__ shift) {
    const int f = blockIdx.x;
    const int p = threadIdx.x;
    float s = psum[p * NF + f];
    float q = psq[p * NF + f];
    #pragma unroll
    for (int o = 32; o > 0; o >>= 1) {
        s += __shfl_down(s, o, 64);
        q += __shfl_down(q, o, 64);
    }
    __shared__ float rs[4], rq[4];
    const int wv = p >> 6;
    if ((p & 63) == 0) { rs[wv] = s; rq[wv] = q; }
    __syncthreads();
    if (p == 0) {
        float S = rs[0] + rs[1] + rs[2] + rs[3];
        float Q = rq[0] + rq[1] + rq[2] + rq[3];
        float mean = S * (1.0f / NB);
        float var = Q * (1.0f / NB) - mean * mean;
        float sc = gamma[f] * rsqrtf(var + 1e-5f);
        scale[f] = sc;
        shift[f] = beta[f] - mean * sc;
    }
}

// K4: BN-apply + LeakyReLU + concat + FC(162->2) + softmax.
__global__ __launch_bounds__(256) void k_fc(
        const float* __restrict__ flat, const float* __restrict__ scale,
        const float* __restrict__ shift, const float* __restrict__ ag,
        const float* __restrict__ fcw, const float* __restrict__ fcb,
        float* __restrict__ out) {
    const int lane = threadIdx.x & 63;
    const int b = blockIdx.x * 4 + (threadIdx.x >> 6);
    const float* fr = flat + (size_t)b * NF;
    float p0 = 0.0f, p1 = 0.0f;
    for (int f = lane; f < NF; f += 64) {
        float xn = fr[f] * scale[f] + shift[f];
        float a = xn >= 0.0f ? xn : 0.01f * xn;
        p0 += a * fcw[f];
        p1 += a * fcw[162 + f];
    }
    #pragma unroll
    for (int o = 32; o > 0; o >>= 1) {
        p0 += __shfl_down(p0, o, 64);
        p1 += __shfl_down(p1, o, 64);
    }
    if (lane == 0) {
        float a0 = ag[(size_t)b * 2 + 0], a1 = ag[(size_t)b * 2 + 1];
        float l0 = p0 + a0 * fcw[160] + a1 * fcw[161] + fcb[0];
        float l1 = p1 + a0 * fcw[162 + 160] + a1 * fcw[162 + 161] + fcb[1];
        float m = fmaxf(l0, l1);
        float e0 = __expf(l0 - m), e1 = __expf(l1 - m);
        float inv = 1.0f / (e0 + e1);
        out[(size_t)b * 2 + 0] = e0 * inv;
        out[(size_t)b * 2 + 1] = e1 * inv;
    }
}

extern "C" void kernel_launch(void* const* d_in, const int* in_sizes, int n_in,
                              void* d_out, int out_size, void* d_ws, size_t ws_size,
                              hipStream_t stream) {
    const float* x     = (const float*)d_in[0];
    const float* ag    = (const float*)d_in[1];
    const float* wih0  = (const float*)d_in[2];
    const float* whh0  = (const float*)d_in[3];
    const float* bih0  = (const float*)d_in[4];
    const float* bhh0  = (const float*)d_in[5];
    const float* wih1  = (const float*)d_in[6];
    const float* whh1  = (const float*)d_in[7];
    const float* bih1  = (const float*)d_in[8];
    const float* bhh1  = (const float*)d_in[9];
    const float* gamma = (const float*)d_in[10];
    const float* beta  = (const float*)d_in[11];
    const float* fcw   = (const float*)d_in[12];
    const float* fcb   = (const float*)d_in[13];
    float* out = (float*)d_out;

    float* ws = (float*)d_ws;
    float* xg0   = ws;                       // 10,485,760 floats
    float* flat  = ws + 10485760;            //  2,621,440 floats
    float* psum  = ws + 13107200;            //     40,960 floats
    float* psq   = ws + 13148160;            //     40,960 floats
    float* scale = ws + 13189120;            //        160
    float* shift = ws + 13189280;            //        160

    k_proj<<<dim3(1280), dim3(256), 0, stream>>>(x, wih0, bih0, bhh0, xg0);
    k_lstm<<<dim3(4096), dim3(256), 0, stream>>>(xg0, whh0, wih1, whh1, bih1, bhh1, flat);
    k_bnA<<<dim3(256), dim3(192), 0, stream>>>(flat, psum, psq);
    k_bnB<<<dim3(160), dim3(256), 0, stream>>>(psum, psq, gamma, beta, scale, shift);
    k_fc<<<dim3(4096), dim3(256), 0, stream>>>(flat, scale, shift, ag, fcw, fcb, out);
}

// Round 4
// 112.591 us; speedup vs baseline: 1.9544x; 1.0307x over previous
//
#include <hip/hip_runtime.h>

#define NB 16384
#define TT 10
#define DIN 256
#define HH 16
#define NG 64      // 4*H
#define NF 160     // T*H

typedef __attribute__((ext_vector_type(8))) _Float16 half8;
typedef __attribute__((ext_vector_type(4))) float f32x4;

__device__ __forceinline__ float sig_(float x) {
    return 1.0f / (1.0f + __expf(-x));
}
__device__ __forceinline__ float tanh_(float x) {
    x = fminf(fmaxf(x, -15.0f), 15.0f);
    float e = __expf(2.0f * x);
    return (e - 1.0f) / (e + 1.0f);
}
__device__ __forceinline__ float rl_(float v, int l) {
    return __int_as_float(__builtin_amdgcn_readlane(__float_as_int(v), l));
}

// K0: one-time prep. B fragments (fp16) in lane order + fused bias.
// Fragment convention (same as validated R3): lane l holds B[col=c*16+(l&15)]
// [k = s*32 + (l>>4)*8 + j], stored at Bf[(c*8+s)*64 + l].
__global__ __launch_bounds__(256) void k_prep(
        const float* __restrict__ w, const float* __restrict__ bi,
        const float* __restrict__ bh, half8* __restrict__ Bf,
        float* __restrict__ bsum) {
    const int fi = blockIdx.x * 256 + threadIdx.x;   // 0..2047
    const int c = fi >> 9;
    const int s = (fi >> 6) & 7;
    const int ll = fi & 63;
    const int row = c * 16 + (ll & 15);
    const int k0 = s * 32 + ((ll >> 4) << 3);
    const float* wp = w + (size_t)row * DIN + k0;
    float4 a = *(const float4*)wp;
    float4 b = *(const float4*)(wp + 4);
    half8 h;
    h[0] = (_Float16)a.x; h[1] = (_Float16)a.y;
    h[2] = (_Float16)a.z; h[3] = (_Float16)a.w;
    h[4] = (_Float16)b.x; h[5] = (_Float16)b.y;
    h[6] = (_Float16)b.z; h[7] = (_Float16)b.w;
    Bf[fi] = h;
    if (blockIdx.x == 0 && threadIdx.x < NG)
        bsum[threadIdx.x] = bi[threadIdx.x] + bh[threadIdx.x];
}

// K1: xg = x . w^T + bias via f16 MFMA (hi+lo split for x).
// No LDS, no barrier: B fragments read per-lane from global (L2-hot, 32 KB).
// One wave = 32 rows x 64 cols. Output stored in C-fragment layout:
//   addr = tile*1024 + c*256 + l*4 + r,  tile=row>>4,
//   value (row = tile*16 + (l>>4)*4 + r, col = c*16 + (l&15)).
__global__ __launch_bounds__(256) void k_proj(
        const float* __restrict__ x, const half8* __restrict__ Bf,
        const float* __restrict__ bsum, float* __restrict__ xgF) {
    const int l = threadIdx.x & 63;
    const int wid = (blockIdx.x * 256 + threadIdx.x) >> 6;  // global wave id
    const int row0 = wid * 32;
    const int rowA0 = row0 + (l & 15);
    const int kb = (l >> 4) << 3;

    f32x4 acc[2][4];
    #pragma unroll
    for (int m = 0; m < 2; ++m)
        #pragma unroll
        for (int c = 0; c < 4; ++c) acc[m][c] = (f32x4)0.0f;

    #pragma unroll
    for (int s = 0; s < 8; ++s) {
        const int k0 = s * 32 + kb;
        half8 ah[2], al[2];
        #pragma unroll
        for (int m = 0; m < 2; ++m) {
            const float* xp = x + (size_t)(rowA0 + m * 16) * DIN + k0;
            float4 a = *(const float4*)xp;
            float4 b = *(const float4*)(xp + 4);
            float f[8] = {a.x, a.y, a.z, a.w, b.x, b.y, b.z, b.w};
            #pragma unroll
            for (int j = 0; j < 8; ++j) {
                _Float16 hi = (_Float16)f[j];
                ah[m][j] = hi;
                al[m][j] = (_Float16)(f[j] - (float)hi);
            }
        }
        #pragma unroll
        for (int c = 0; c < 4; ++c) {
            half8 bf = Bf[(c * 8 + s) * 64 + l];
            #pragma unroll
            for (int m = 0; m < 2; ++m) {
                acc[m][c] = __builtin_amdgcn_mfma_f32_16x16x32_f16(ah[m], bf, acc[m][c], 0, 0, 0);
                acc[m][c] = __builtin_amdgcn_mfma_f32_16x16x32_f16(al[m], bf, acc[m][c], 0, 0, 0);
            }
        }
    }

    const int tile0 = row0 >> 4;
    #pragma unroll
    for (int m = 0; m < 2; ++m) {
        #pragma unroll
        for (int c = 0; c < 4; ++c) {
            const float bb = bsum[c * 16 + (l & 15)];
            f32x4 v = acc[m][c];
            v.x += bb; v.y += bb; v.z += bb; v.w += bb;
            *(f32x4*)(xgF + (size_t)(tile0 + m) * 1024 + c * 256 + l * 4) = v;
        }
    }
}

// K2: fused 2-layer LSTM recurrence. xg read from fragment layout, all 10
// timesteps prefetched up front (off the recurrence critical path).
__global__ __launch_bounds__(256) void k_lstm(
        const float* __restrict__ xgF, const float* __restrict__ whh0,
        const float* __restrict__ wih1, const float* __restrict__ whh1,
        const float* __restrict__ bi1, const float* __restrict__ bh1,
        float* __restrict__ flat) {
    const int lane = threadIdx.x & 63;
    const int b = blockIdx.x * 4 + (threadIdx.x >> 6);
    const int g = lane;

    // prefetch xg for all t (fragment-layout inverse addressing)
    float xv[TT];
    #pragma unroll
    for (int t = 0; t < TT; ++t) {
        const int row = b * TT + t;
        const int addr = ((row >> 4) << 10) + ((g >> 4) << 8) +
                         (((row >> 2) & 3) << 6) + ((g & 15) << 2) + (row & 3);
        xv[t] = xgF[addr];
    }

    float w0[16], w1[16], w2[16];
    #pragma unroll
    for (int q = 0; q < 4; ++q) {
        float4 v0 = *(const float4*)(whh0 + g * HH + q * 4);
        w0[q*4+0] = v0.x; w0[q*4+1] = v0.y; w0[q*4+2] = v0.z; w0[q*4+3] = v0.w;
        float4 v1 = *(const float4*)(wih1 + g * HH + q * 4);
        w1[q*4+0] = v1.x; w1[q*4+1] = v1.y; w1[q*4+2] = v1.z; w1[q*4+3] = v1.w;
        float4 v2 = *(const float4*)(whh1 + g * HH + q * 4);
        w2[q*4+0] = v2.x; w2[q*4+1] = v2.y; w2[q*4+2] = v2.z; w2[q*4+3] = v2.w;
    }
    const float bias1 = bi1[g] + bh1[g];
    const bool isg = (g & 48) == 32;
    float h0 = 0.0f, c0 = 0.0f, h1 = 0.0f, c1 = 0.0f;

    for (int t = 0; t < TT; ++t) {
        float s0 = xv[t], s1 = 0.0f, s2 = 0.0f, s3 = 0.0f;
        #pragma unroll
        for (int q = 0; q < 4; ++q) {
            s0 += rl_(h0, 4*q + 0) * w0[4*q + 0];
            s1 += rl_(h0, 4*q + 1) * w0[4*q + 1];
            s2 += rl_(h0, 4*q + 2) * w0[4*q + 2];
            s3 += rl_(h0, 4*q + 3) * w0[4*q + 3];
        }
        float gate = (s0 + s1) + (s2 + s3);
        float a = isg ? tanh_(gate) : sig_(gate);
        float af = __shfl_down(a, 16, 64);
        float ac = __shfl_down(a, 32, 64);
        float ao = __shfl_down(a, 48, 64);
        c0 = af * c0 + a * ac;
        h0 = ao * tanh_(c0);

        float u0 = bias1, u1 = 0.0f, u2 = 0.0f, u3 = 0.0f;
        float v0 = 0.0f, v1 = 0.0f, v2 = 0.0f, v3 = 0.0f;
        #pragma unroll
        for (int q = 0; q < 4; ++q) {
            u0 += rl_(h0, 4*q + 0) * w1[4*q + 0];
            u1 += rl_(h0, 4*q + 1) * w1[4*q + 1];
            u2 += rl_(h0, 4*q + 2) * w1[4*q + 2];
            u3 += rl_(h0, 4*q + 3) * w1[4*q + 3];
            v0 += rl_(h1, 4*q + 0) * w2[4*q + 0];
            v1 += rl_(h1, 4*q + 1) * w2[4*q + 1];
            v2 += rl_(h1, 4*q + 2) * w2[4*q + 2];
            v3 += rl_(h1, 4*q + 3) * w2[4*q + 3];
        }
        float gate1 = ((u0 + v0) + (u1 + v1)) + ((u2 + v2) + (u3 + v3));
        float a1 = isg ? tanh_(gate1) : sig_(gate1);
        af = __shfl_down(a1, 16, 64);
        ac = __shfl_down(a1, 32, 64);
        ao = __shfl_down(a1, 48, 64);
        c1 = af * c1 + a1 * ac;
        h1 = ao * tanh_(c1);

        if (g < HH) flat[(size_t)b * NF + t * HH + g] = h1;
    }
}

// K3a: per-chunk partial sums for BN stats, coalesced reads.
__global__ __launch_bounds__(192) void k_bnA(
        const float* __restrict__ flat, float* __restrict__ psum,
        float* __restrict__ psq) {
    const int f = threadIdx.x;
    if (f >= NF) return;
    const int p = blockIdx.x;
    const float* base = flat + (size_t)p * 64 * NF + f;
    float s0 = 0.0f, s1 = 0.0f, q0 = 0.0f, q1 = 0.0f;
    #pragma unroll 4
    for (int r = 0; r < 64; r += 2) {
        float a = base[(size_t)r * NF];
        float b2 = base[(size_t)(r + 1) * NF];
        s0 += a; q0 += a * a;
        s1 += b2; q1 += b2 * b2;
    }
    psum[p * NF + f] = s0 + s1;
    psq[p * NF + f] = q0 + q1;
}

// K3b: reduce partials -> fused scale/shift.
__global__ __launch_bounds__(256) void k_bnB(
        const float* __restrict__ psum, const float* __restrict__ psq,
        const float* __restrict__ gamma, const float* __restrict__ beta,
        float* __restrict__ scale, float* __restrict__ shift) {
    const int f = blockIdx.x;
    const int p = threadIdx.x;
    float s = psum[p * NF + f];
    float q = psq[p * NF + f];
    #pragma unroll
    for (int o = 32; o > 0; o >>= 1) {
        s += __shfl_down(s, o, 64);
        q += __shfl_down(q, o, 64);
    }
    __shared__ float rs[4], rq[4];
    const int wv = p >> 6;
    if ((p & 63) == 0) { rs[wv] = s; rq[wv] = q; }
    __syncthreads();
    if (p == 0) {
        float S = rs[0] + rs[1] + rs[2] + rs[3];
        float Q = rq[0] + rq[1] + rq[2] + rq[3];
        float mean = S * (1.0f / NB);
        float var = Q * (1.0f / NB) - mean * mean;
        float sc = gamma[f] * rsqrtf(var + 1e-5f);
        scale[f] = sc;
        shift[f] = beta[f] - mean * sc;
    }
}

// K4: BN-apply + LeakyReLU + concat + FC(162->2) + softmax.
__global__ __launch_bounds__(256) void k_fc(
        const float* __restrict__ flat, const float* __restrict__ scale,
        const float* __restrict__ shift, const float* __restrict__ ag,
        const float* __restrict__ fcw, const float* __restrict__ fcb,
        float* __restrict__ out) {
    const int lane = threadIdx.x & 63;
    const int b = blockIdx.x * 4 + (threadIdx.x >> 6);
    const float* fr = flat + (size_t)b * NF;
    float p0 = 0.0f, p1 = 0.0f;
    for (int f = lane; f < NF; f += 64) {
        float xn = fr[f] * scale[f] + shift[f];
        float a = xn >= 0.0f ? xn : 0.01f * xn;
        p0 += a * fcw[f];
        p1 += a * fcw[162 + f];
    }
    #pragma unroll
    for (int o = 32; o > 0; o >>= 1) {
        p0 += __shfl_down(p0, o, 64);
        p1 += __shfl_down(p1, o, 64);
    }
    if (lane == 0) {
        float a0 = ag[(size_t)b * 2 + 0], a1 = ag[(size_t)b * 2 + 1];
        float l0 = p0 + a0 * fcw[160] + a1 * fcw[161] + fcb[0];
        float l1 = p1 + a0 * fcw[162 + 160] + a1 * fcw[162 + 161] + fcb[1];
        float m = fmaxf(l0, l1);
        float e0 = __expf(l0 - m), e1 = __expf(l1 - m);
        float inv = 1.0f / (e0 + e1);
        out[(size_t)b * 2 + 0] = e0 * inv;
        out[(size_t)b * 2 + 1] = e1 * inv;
    }
}

extern "C" void kernel_launch(void* const* d_in, const int* in_sizes, int n_in,
                              void* d_out, int out_size, void* d_ws, size_t ws_size,
                              hipStream_t stream) {
    const float* x     = (const float*)d_in[0];
    const float* ag    = (const float*)d_in[1];
    const float* wih0  = (const float*)d_in[2];
    const float* whh0  = (const float*)d_in[3];
    const float* bih0  = (const float*)d_in[4];
    const float* bhh0  = (const float*)d_in[5];
    const float* wih1  = (const float*)d_in[6];
    const float* whh1  = (const float*)d_in[7];
    const float* bih1  = (const float*)d_in[8];
    const float* bhh1  = (const float*)d_in[9];
    const float* gamma = (const float*)d_in[10];
    const float* beta  = (const float*)d_in[11];
    const float* fcw   = (const float*)d_in[12];
    const float* fcb   = (const float*)d_in[13];
    float* out = (float*)d_out;

    float* ws = (float*)d_ws;
    float* xgF   = ws;                       // 10,485,760 floats (frag layout)
    float* flat  = ws + 10485760;            //  2,621,440 floats
    float* psum  = ws + 13107200;            //     40,960 floats
    float* psq   = ws + 13148160;            //     40,960 floats
    float* scale = ws + 13189120;            //        160
    float* shift = ws + 13189280;            //        160
    half8* Bf    = (half8*)(ws + 13189440);  //      8,192 floats (32 KB, 16B-aligned)
    float* bsum  = ws + 13197632;            //         64

    k_prep<<<dim3(8),    dim3(256), 0, stream>>>(wih0, bih0, bhh0, Bf, bsum);
    k_proj<<<dim3(1280), dim3(256), 0, stream>>>(x, Bf, bsum, xgF);
    k_lstm<<<dim3(4096), dim3(256), 0, stream>>>(xgF, whh0, wih1, whh1, bih1, bhh1, flat);
    k_bnA<<<dim3(256),  dim3(192), 0, stream>>>(flat, psum, psq);
    k_bnB<<<dim3(160),  dim3(256), 0, stream>>>(psum, psq, gamma, beta, scale, shift);
    k_fc<<<dim3(4096),  dim3(256), 0, stream>>>(flat, scale, shift, ag, fcw, fcb, out);
}

// Round 5
// 110.026 us; speedup vs baseline: 2.0000x; 1.0233x over previous
//
#include <hip/hip_runtime.h>

#define NB 16384
#define TT 10
#define DIN 256
#define HH 16
#define NG 64      // 4*H
#define NF 160     // T*H
#define SPB 16     // samples per block
#define RPB 160    // rows per block (SPB*TT)
#define NBLK 1024  // NB/SPB

typedef __attribute__((ext_vector_type(8))) _Float16 half8;
typedef __attribute__((ext_vector_type(4))) float f32x4;

__device__ __forceinline__ float rl_(float v, int l) {
    return __int_as_float(__builtin_amdgcn_readlane(__float_as_int(v), l));
}

// K0: one-time prep. B fragments (fp16, lane order) + fused layer-0 bias.
// Fragment convention (validated R3/R4): lane l holds B[col=c*16+(l&15)]
// [k = s*32 + (l>>4)*8 + j], stored at Bf[(c*8+s)*64 + l].
__global__ __launch_bounds__(256) void k_prep(
        const float* __restrict__ w, const float* __restrict__ bi,
        const float* __restrict__ bh, half8* __restrict__ Bf,
        float* __restrict__ bsum) {
    const int fi = blockIdx.x * 256 + threadIdx.x;   // 0..2047
    const int c = fi >> 9;
    const int s = (fi >> 6) & 7;
    const int ll = fi & 63;
    const int row = c * 16 + (ll & 15);
    const int k0 = s * 32 + ((ll >> 4) << 3);
    const float* wp = w + (size_t)row * DIN + k0;
    float4 a = *(const float4*)wp;
    float4 b = *(const float4*)(wp + 4);
    half8 h;
    h[0] = (_Float16)a.x; h[1] = (_Float16)a.y;
    h[2] = (_Float16)a.z; h[3] = (_Float16)a.w;
    h[4] = (_Float16)b.x; h[5] = (_Float16)b.y;
    h[6] = (_Float16)b.z; h[7] = (_Float16)b.w;
    Bf[fi] = h;
    if (blockIdx.x == 0 && threadIdx.x < NG)
        bsum[threadIdx.x] = bi[threadIdx.x] + bh[threadIdx.x];
}

// K1: FUSED proj (f16 MFMA, hi/lo split) + 2-layer LSTM + BN partial sums.
// Block = 16 samples = 160 rows. x staged per 64-wide K-chunk into LDS with
// coalesced loads + XOR swizzle (byte ^= (row&7)<<4, 16B granularity).
// xg stays in LDS ([160][65] f32) — never round-trips to global.
__global__ __launch_bounds__(256) void k_main(
        const float* __restrict__ x, const half8* __restrict__ Bf,
        const float* __restrict__ bsum,
        const float* __restrict__ whh0, const float* __restrict__ wih1,
        const float* __restrict__ whh1, const float* __restrict__ bi1,
        const float* __restrict__ bh1,
        float* __restrict__ flat, float* __restrict__ psum,
        float* __restrict__ psq) {
    __shared__ float smem[RPB * 65];   // 41.6 KB; aliased: staging / xg / bn
    const int tid = threadIdx.x;
    const int l = tid & 63;
    const int wv = tid >> 6;
    const int blk = blockIdx.x;
    const size_t xbase = (size_t)blk * RPB * DIN;

    // ---------------- phase A: projection via MFMA ----------------
    f32x4 acc[3][4];
    #pragma unroll
    for (int ti = 0; ti < 3; ++ti)
        #pragma unroll
        for (int c = 0; c < 4; ++c) acc[ti][c] = (f32x4)0.0f;

    const int srow = tid >> 4;          // staging row within pass
    const int scol = (tid & 15) * 4;    // staging f32 col within chunk

    for (int kc = 0; kc < 4; ++kc) {
        // stage 160x64 f32, fully coalesced (16 lanes = 256B contiguous)
        #pragma unroll
        for (int pass = 0; pass < 10; ++pass) {
            const int row = pass * 16 + srow;
            f32x4 v = *(const f32x4*)(x + xbase + (size_t)row * DIN + kc * 64 + scol);
            const int byte = (row * 256 + scol * 4) ^ ((row & 7) << 4);
            *(f32x4*)((char*)smem + byte) = v;
        }
        __syncthreads();

        // B fragments for this chunk (global, L2-hot, lane-contiguous)
        half8 bfr[2][4];
        #pragma unroll
        for (int sl = 0; sl < 2; ++sl)
            #pragma unroll
            for (int c = 0; c < 4; ++c)
                bfr[sl][c] = Bf[(c * 8 + kc * 2 + sl) * 64 + l];

        #pragma unroll
        for (int ti = 0; ti < 3; ++ti) {
            const int tile = wv + ti * 4;
            if (tile < 10) {
                #pragma unroll
                for (int sl = 0; sl < 2; ++sl) {
                    const int row = tile * 16 + (l & 15);
                    const int base = row * 256 + (sl * 32 + ((l >> 4) << 3)) * 4;
                    const int swz = (row & 7) << 4;
                    f32x4 va = *(const f32x4*)((char*)smem + (base ^ swz));
                    f32x4 vb = *(const f32x4*)((char*)smem + ((base + 16) ^ swz));
                    float fv[8] = {va.x, va.y, va.z, va.w, vb.x, vb.y, vb.z, vb.w};
                    half8 ah, al;
                    #pragma unroll
                    for (int j = 0; j < 8; ++j) {
                        _Float16 hi = (_Float16)fv[j];
                        ah[j] = hi;
                        al[j] = (_Float16)(fv[j] - (float)hi);
                    }
                    #pragma unroll
                    for (int c = 0; c < 4; ++c) {
                        acc[ti][c] = __builtin_amdgcn_mfma_f32_16x16x32_f16(ah, bfr[sl][c], acc[ti][c], 0, 0, 0);
                        acc[ti][c] = __builtin_amdgcn_mfma_f32_16x16x32_f16(al, bfr[sl][c], acc[ti][c], 0, 0, 0);
                    }
                }
            }
        }
        __syncthreads();
    }

    // write xg -> LDS [row][65] (C-layout: col=c*16+(l&15), row=(l>>4)*4+r)
    #pragma unroll
    for (int ti = 0; ti < 3; ++ti) {
        const int tile = wv + ti * 4;
        if (tile < 10) {
            #pragma unroll
            for (int c = 0; c < 4; ++c) {
                const int col = c * 16 + (l & 15);
                const int rb = tile * 16 + ((l >> 4) << 2);
                #pragma unroll
                for (int r = 0; r < 4; ++r)
                    smem[(rb + r) * 65 + col] = acc[ti][c][r];
            }
        }
    }
    __syncthreads();

    // ---------------- phase B: 2-layer LSTM recurrence ----------------
    // lane = gate g; state h/c on lanes 0-15; 4 samples per wave (ILP).
    float w0[16], w1[16], w2[16];
    #pragma unroll
    for (int q = 0; q < 4; ++q) {
        float4 v0 = *(const float4*)(whh0 + l * HH + q * 4);
        w0[q*4+0] = v0.x; w0[q*4+1] = v0.y; w0[q*4+2] = v0.z; w0[q*4+3] = v0.w;
        float4 v1 = *(const float4*)(wih1 + l * HH + q * 4);
        w1[q*4+0] = v1.x; w1[q*4+1] = v1.y; w1[q*4+2] = v1.z; w1[q*4+3] = v1.w;
        float4 v2 = *(const float4*)(whh1 + l * HH + q * 4);
        w2[q*4+0] = v2.x; w2[q*4+1] = v2.y; w2[q*4+2] = v2.z; w2[q*4+3] = v2.w;
    }
    const float bias0 = bsum[l];
    const float bias1 = bi1[l] + bh1[l];
    const bool isg = (l & 48) == 32;     // candidate gate -> tanh
    const float m1 = isg ? 2.0f : 1.0f;  // a = m1*sig(m1*z) + b2 unifies sig/tanh
    const float b2 = isg ? -1.0f : 0.0f;

    float h0[4] = {0,0,0,0}, c0[4] = {0,0,0,0};
    float h1a[4] = {0,0,0,0}, c1a[4] = {0,0,0,0};
    float fs[TT], fq[TT];
    #pragma unroll
    for (int t = 0; t < TT; ++t) { fs[t] = 0.0f; fq[t] = 0.0f; }

    const int sb = wv * 4;   // first local sample of this wave
    #pragma unroll
    for (int t = 0; t < TT; ++t) {
        #pragma unroll
        for (int sm = 0; sm < 4; ++sm) {
            const int rl0 = (sb + sm) * TT + t;
            // layer 0
            float s0 = smem[rl0 * 65 + l] + bias0, s1 = 0.0f, s2 = 0.0f, s3 = 0.0f;
            #pragma unroll
            for (int q = 0; q < 4; ++q) {
                s0 += rl_(h0[sm], 4*q + 0) * w0[4*q + 0];
                s1 += rl_(h0[sm], 4*q + 1) * w0[4*q + 1];
                s2 += rl_(h0[sm], 4*q + 2) * w0[4*q + 2];
                s3 += rl_(h0[sm], 4*q + 3) * w0[4*q + 3];
            }
            float z = ((s0 + s1) + (s2 + s3)) * m1;
            float a = m1 / (1.0f + __expf(-z)) + b2;
            float af = __shfl_down(a, 16, 64);
            float ac = __shfl_down(a, 32, 64);
            float ao = __shfl_down(a, 48, 64);
            c0[sm] = af * c0[sm] + a * ac;
            float e0 = __expf(2.0f * c0[sm]);
            h0[sm] = ao * (1.0f - 2.0f / (e0 + 1.0f));
            // layer 1
            float u0 = bias1, u1 = 0.0f, u2 = 0.0f, u3 = 0.0f;
            float v0 = 0.0f, v1 = 0.0f, v2 = 0.0f, v3 = 0.0f;
            #pragma unroll
            for (int q = 0; q < 4; ++q) {
                u0 += rl_(h0[sm], 4*q + 0) * w1[4*q + 0];
                u1 += rl_(h0[sm], 4*q + 1) * w1[4*q + 1];
                u2 += rl_(h0[sm], 4*q + 2) * w1[4*q + 2];
                u3 += rl_(h0[sm], 4*q + 3) * w1[4*q + 3];
                v0 += rl_(h1a[sm], 4*q + 0) * w2[4*q + 0];
                v1 += rl_(h1a[sm], 4*q + 1) * w2[4*q + 1];
                v2 += rl_(h1a[sm], 4*q + 2) * w2[4*q + 2];
                v3 += rl_(h1a[sm], 4*q + 3) * w2[4*q + 3];
            }
            float z1 = (((u0 + v0) + (u1 + v1)) + ((u2 + v2) + (u3 + v3))) * m1;
            float a1 = m1 / (1.0f + __expf(-z1)) + b2;
            af = __shfl_down(a1, 16, 64);
            ac = __shfl_down(a1, 32, 64);
            ao = __shfl_down(a1, 48, 64);
            c1a[sm] = af * c1a[sm] + a1 * ac;
            float e1 = __expf(2.0f * c1a[sm]);
            float h1v = ao * (1.0f - 2.0f / (e1 + 1.0f));
            h1a[sm] = h1v;
            if (l < HH)
                flat[(size_t)(blk * SPB + sb + sm) * NF + t * HH + l] = h1v;
            fs[t] += h1v; fq[t] += h1v * h1v;
        }
    }

    // ---------------- phase C: BN partial sums (per-block) ----------------
    __syncthreads();   // all xg reads done; smem reusable
    if (l < HH) {
        #pragma unroll
        for (int t = 0; t < TT; ++t) {
            smem[wv * NF + t * HH + l] = fs[t];
            smem[4 * NF + wv * NF + t * HH + l] = fq[t];
        }
    }
    __syncthreads();
    if (tid < NF) {
        float S = smem[tid] + smem[NF + tid] + smem[2*NF + tid] + smem[3*NF + tid];
        float Q = smem[4*NF + tid] + smem[5*NF + tid] + smem[6*NF + tid] + smem[7*NF + tid];
        psum[(size_t)blk * NF + tid] = S;
        psq[(size_t)blk * NF + tid] = Q;
    }
}

// K2: reduce 1024 block-partials -> fused BN scale/shift.
__global__ __launch_bounds__(256) void k_bnB(
        const float* __restrict__ psum, const float* __restrict__ psq,
        const float* __restrict__ gamma, const float* __restrict__ beta,
        float* __restrict__ scale, float* __restrict__ shift) {
    const int f = blockIdx.x;
    const int tid = threadIdx.x;
    float s = 0.0f, q = 0.0f;
    #pragma unroll
    for (int j = 0; j < 4; ++j) {
        const int p = tid + j * 256;
        s += psum[(size_t)p * NF + f];
        q += psq[(size_t)p * NF + f];
    }
    #pragma unroll
    for (int o = 32; o > 0; o >>= 1) {
        s += __shfl_down(s, o, 64);
        q += __shfl_down(q, o, 64);
    }
    __shared__ float rs[4], rq[4];
    const int wv = tid >> 6;
    if ((tid & 63) == 0) { rs[wv] = s; rq[wv] = q; }
    __syncthreads();
    if (tid == 0) {
        float S = rs[0] + rs[1] + rs[2] + rs[3];
        float Q = rq[0] + rq[1] + rq[2] + rq[3];
        float mean = S * (1.0f / NB);
        float var = Q * (1.0f / NB) - mean * mean;
        float sc = gamma[f] * rsqrtf(var + 1e-5f);
        scale[f] = sc;
        shift[f] = beta[f] - mean * sc;
    }
}

// K3: BN-apply + LeakyReLU + concat + FC(162->2) + softmax.
__global__ __launch_bounds__(256) void k_fc(
        const float* __restrict__ flat, const float* __restrict__ scale,
        const float* __restrict__ shift, const float* __restrict__ ag,
        const float* __restrict__ fcw, const float* __restrict__ fcb,
        float* __restrict__ out) {
    const int lane = threadIdx.x & 63;
    const int b = blockIdx.x * 4 + (threadIdx.x >> 6);
    const float* fr = flat + (size_t)b * NF;
    float p0 = 0.0f, p1 = 0.0f;
    for (int f = lane; f < NF; f += 64) {
        float xn = fr[f] * scale[f] + shift[f];
        float a = xn >= 0.0f ? xn : 0.01f * xn;
        p0 += a * fcw[f];
        p1 += a * fcw[162 + f];
    }
    #pragma unroll
    for (int o = 32; o > 0; o >>= 1) {
        p0 += __shfl_down(p0, o, 64);
        p1 += __shfl_down(p1, o, 64);
    }
    if (lane == 0) {
        float a0 = ag[(size_t)b * 2 + 0], a1 = ag[(size_t)b * 2 + 1];
        float l0 = p0 + a0 * fcw[160] + a1 * fcw[161] + fcb[0];
        float l1 = p1 + a0 * fcw[162 + 160] + a1 * fcw[162 + 161] + fcb[1];
        float m = fmaxf(l0, l1);
        float e0 = __expf(l0 - m), e1 = __expf(l1 - m);
        float inv = 1.0f / (e0 + e1);
        out[(size_t)b * 2 + 0] = e0 * inv;
        out[(size_t)b * 2 + 1] = e1 * inv;
    }
}

extern "C" void kernel_launch(void* const* d_in, const int* in_sizes, int n_in,
                              void* d_out, int out_size, void* d_ws, size_t ws_size,
                              hipStream_t stream) {
    const float* x     = (const float*)d_in[0];
    const float* ag    = (const float*)d_in[1];
    const float* wih0  = (const float*)d_in[2];
    const float* whh0  = (const float*)d_in[3];
    const float* bih0  = (const float*)d_in[4];
    const float* bhh0  = (const float*)d_in[5];
    const float* wih1  = (const float*)d_in[6];
    const float* whh1  = (const float*)d_in[7];
    const float* bih1  = (const float*)d_in[8];
    const float* bhh1  = (const float*)d_in[9];
    const float* gamma = (const float*)d_in[10];
    const float* beta  = (const float*)d_in[11];
    const float* fcw   = (const float*)d_in[12];
    const float* fcb   = (const float*)d_in[13];
    float* out = (float*)d_out;

    float* ws = (float*)d_ws;
    float* flat  = ws;                        //  2,621,440 floats
    float* psum  = ws + 2621440;              //    163,840
    float* psq   = ws + 2785280;              //    163,840
    float* scale = ws + 2949120;              //        160
    float* shift = ws + 2949280;              //        160
    half8* Bf    = (half8*)(ws + 2949440);    //  8,192 floats (32 KB, 16B-aligned)
    float* bsum  = ws + 2957632;              //         64

    k_prep<<<dim3(8),    dim3(256), 0, stream>>>(wih0, bih0, bhh0, Bf, bsum);
    k_main<<<dim3(NBLK), dim3(256), 0, stream>>>(x, Bf, bsum, whh0, wih1, whh1,
                                                 bih1, bhh1, flat, psum, psq);
    k_bnB<<<dim3(NF),   dim3(256), 0, stream>>>(psum, psq, gamma, beta, scale, shift);
    k_fc<<<dim3(4096),  dim3(256), 0, stream>>>(flat, scale, shift, ag, fcw, fcb, out);
}

// Round 6
// 103.478 us; speedup vs baseline: 2.1265x; 1.0633x over previous
//
#include <hip/hip_runtime.h>

#define NB 16384
#define TT 10
#define DIN 256
#define HH 16
#define NG 64      // 4*H
#define NF 160     // T*H

typedef __attribute__((ext_vector_type(8))) _Float16 half8;
typedef __attribute__((ext_vector_type(4))) float f32x4;

__device__ __forceinline__ float rl_(float v, int l) {
    return __int_as_float(__builtin_amdgcn_readlane(__float_as_int(v), l));
}

// K0: one-time prep. B fragments (fp16, lane order) + fused layer-0 bias.
// Fragment convention (validated R3/R4): lane l holds B[col=c*16+(l&15)]
// [k = s*32 + (l>>4)*8 + j], stored at Bf[(c*8+s)*64 + l].
__global__ __launch_bounds__(256) void k_prep(
        const float* __restrict__ w, const float* __restrict__ bi,
        const float* __restrict__ bh, half8* __restrict__ Bf,
        float* __restrict__ bsum) {
    const int fi = blockIdx.x * 256 + threadIdx.x;   // 0..2047
    const int c = fi >> 9;
    const int s = (fi >> 6) & 7;
    const int ll = fi & 63;
    const int row = c * 16 + (ll & 15);
    const int k0 = s * 32 + ((ll >> 4) << 3);
    const float* wp = w + (size_t)row * DIN + k0;
    float4 a = *(const float4*)wp;
    float4 b = *(const float4*)(wp + 4);
    half8 h;
    h[0] = (_Float16)a.x; h[1] = (_Float16)a.y;
    h[2] = (_Float16)a.z; h[3] = (_Float16)a.w;
    h[4] = (_Float16)b.x; h[5] = (_Float16)b.y;
    h[6] = (_Float16)b.z; h[7] = (_Float16)b.w;
    Bf[fi] = h;
    if (blockIdx.x == 0 && threadIdx.x < NG)
        bsum[threadIdx.x] = bi[threadIdx.x] + bh[threadIdx.x];
}

// K1: xg = x . w^T + bias via f16 MFMA (hi/lo split).
// MLP-first design: each wave owns 16 rows and issues ALL 16 x-loads
// (full K=256 slice, 64 VGPRs) back-to-back before any use; Bf staged to
// LDS cooperatively (loads issued before x-loads so the ds_write wait
// doesn't drain the x prefetch). No global dependency inside the MFMA loop.
// Output in C-fragment layout: addr = tile*1024 + c*256 + l*4 + r
// (row = tile*16 + (l>>4)*4 + r, col = c*16 + (l&15)).
__global__ __launch_bounds__(256) void k_proj(
        const float* __restrict__ x, const half8* __restrict__ Bf,
        const float* __restrict__ bsum, float* __restrict__ xgF) {
    __shared__ half8 Bl[2048];   // 32 KB
    const int tid = threadIdx.x;
    const int l = tid & 63;

    // 1) issue Bf staging loads (oldest in vm queue)
    half8 breg[8];
    #pragma unroll
    for (int i = 0; i < 8; ++i) breg[i] = Bf[i * 256 + tid];

    // 2) issue the wave's entire x slice: 16 independent dwordx4 loads
    const int wid = (blockIdx.x * 256 + tid) >> 6;   // global wave id
    const int row = wid * 16 + (l & 15);
    const float* xr = x + (size_t)row * DIN + ((l >> 4) << 3);
    f32x4 xa[8], xb[8];
    #pragma unroll
    for (int s = 0; s < 8; ++s) {
        xa[s] = *(const f32x4*)(xr + s * 32);
        xb[s] = *(const f32x4*)(xr + s * 32 + 4);
    }

    // 3) park Bf in LDS (waits only the 8 oldest loads), barrier
    #pragma unroll
    for (int i = 0; i < 8; ++i) Bl[i * 256 + tid] = breg[i];
    __syncthreads();

    // 4) convert + MFMA, purely register/LDS-fed
    f32x4 acc[4];
    #pragma unroll
    for (int c = 0; c < 4; ++c) acc[c] = (f32x4)0.0f;

    #pragma unroll
    for (int s = 0; s < 8; ++s) {
        float fv[8] = {xa[s].x, xa[s].y, xa[s].z, xa[s].w,
                       xb[s].x, xb[s].y, xb[s].z, xb[s].w};
        half8 ah, al;
        #pragma unroll
        for (int j = 0; j < 8; ++j) {
            _Float16 hi = (_Float16)fv[j];
            ah[j] = hi;
            al[j] = (_Float16)(fv[j] - (float)hi);
        }
        #pragma unroll
        for (int c = 0; c < 4; ++c) {
            half8 bf = Bl[(c * 8 + s) * 64 + l];
            acc[c] = __builtin_amdgcn_mfma_f32_16x16x32_f16(ah, bf, acc[c], 0, 0, 0);
            acc[c] = __builtin_amdgcn_mfma_f32_16x16x32_f16(al, bf, acc[c], 0, 0, 0);
        }
    }

    // 5) epilogue: bias + coalesced fragment-layout store (16B/lane)
    #pragma unroll
    for (int c = 0; c < 4; ++c) {
        const float bb = bsum[c * 16 + (l & 15)];
        f32x4 v = acc[c];
        v.x += bb; v.y += bb; v.z += bb; v.w += bb;
        *(f32x4*)(xgF + (size_t)wid * 1024 + c * 256 + l * 4) = v;
    }
}

// K2: fused 2-layer LSTM recurrence. xg read from fragment layout, all 10
// timesteps prefetched up front. Unified activation (validated R5):
// a = m1*sig(m1*z) + b2  (sig for gates, tanh identity for candidate).
__global__ __launch_bounds__(256) void k_lstm(
        const float* __restrict__ xgF, const float* __restrict__ whh0,
        const float* __restrict__ wih1, const float* __restrict__ whh1,
        const float* __restrict__ bi1, const float* __restrict__ bh1,
        float* __restrict__ flat) {
    const int g = threadIdx.x & 63;
    const int b = blockIdx.x * 4 + (threadIdx.x >> 6);

    float xv[TT];
    #pragma unroll
    for (int t = 0; t < TT; ++t) {
        const int row = b * TT + t;
        const int addr = ((row >> 4) << 10) + ((g >> 4) << 8) +
                         (((row >> 2) & 3) << 6) + ((g & 15) << 2) + (row & 3);
        xv[t] = xgF[addr];
    }

    float w0[16], w1[16], w2[16];
    #pragma unroll
    for (int q = 0; q < 4; ++q) {
        float4 v0 = *(const float4*)(whh0 + g * HH + q * 4);
        w0[q*4+0] = v0.x; w0[q*4+1] = v0.y; w0[q*4+2] = v0.z; w0[q*4+3] = v0.w;
        float4 v1 = *(const float4*)(wih1 + g * HH + q * 4);
        w1[q*4+0] = v1.x; w1[q*4+1] = v1.y; w1[q*4+2] = v1.z; w1[q*4+3] = v1.w;
        float4 v2 = *(const float4*)(whh1 + g * HH + q * 4);
        w2[q*4+0] = v2.x; w2[q*4+1] = v2.y; w2[q*4+2] = v2.z; w2[q*4+3] = v2.w;
    }
    const float bias1 = bi1[g] + bh1[g];
    const bool isg = (g & 48) == 32;
    const float m1 = isg ? 2.0f : 1.0f;
    const float b2 = isg ? -1.0f : 0.0f;
    float h0 = 0.0f, c0 = 0.0f, h1 = 0.0f, c1 = 0.0f;

    #pragma unroll
    for (int t = 0; t < TT; ++t) {
        float s0 = xv[t], s1 = 0.0f, s2 = 0.0f, s3 = 0.0f;
        #pragma unroll
        for (int q = 0; q < 4; ++q) {
            s0 += rl_(h0, 4*q + 0) * w0[4*q + 0];
            s1 += rl_(h0, 4*q + 1) * w0[4*q + 1];
            s2 += rl_(h0, 4*q + 2) * w0[4*q + 2];
            s3 += rl_(h0, 4*q + 3) * w0[4*q + 3];
        }
        float z = ((s0 + s1) + (s2 + s3)) * m1;
        float a = m1 / (1.0f + __expf(-z)) + b2;
        float af = __shfl_down(a, 16, 64);
        float ac = __shfl_down(a, 32, 64);
        float ao = __shfl_down(a, 48, 64);
        c0 = af * c0 + a * ac;
        float e0 = __expf(2.0f * c0);
        h0 = ao * (1.0f - 2.0f / (e0 + 1.0f));

        float u0 = bias1, u1 = 0.0f, u2 = 0.0f, u3 = 0.0f;
        float v0 = 0.0f, v1 = 0.0f, v2 = 0.0f, v3 = 0.0f;
        #pragma unroll
        for (int q = 0; q < 4; ++q) {
            u0 += rl_(h0, 4*q + 0) * w1[4*q + 0];
            u1 += rl_(h0, 4*q + 1) * w1[4*q + 1];
            u2 += rl_(h0, 4*q + 2) * w1[4*q + 2];
            u3 += rl_(h0, 4*q + 3) * w1[4*q + 3];
            v0 += rl_(h1, 4*q + 0) * w2[4*q + 0];
            v1 += rl_(h1, 4*q + 1) * w2[4*q + 1];
            v2 += rl_(h1, 4*q + 2) * w2[4*q + 2];
            v3 += rl_(h1, 4*q + 3) * w2[4*q + 3];
        }
        float z1 = (((u0 + v0) + (u1 + v1)) + ((u2 + v2) + (u3 + v3))) * m1;
        float a1 = m1 / (1.0f + __expf(-z1)) + b2;
        af = __shfl_down(a1, 16, 64);
        ac = __shfl_down(a1, 32, 64);
        ao = __shfl_down(a1, 48, 64);
        c1 = af * c1 + a1 * ac;
        float e1 = __expf(2.0f * c1);
        h1 = ao * (1.0f - 2.0f / (e1 + 1.0f));

        if (g < HH) flat[(size_t)b * NF + t * HH + g] = h1;
    }
}

// K3a: per-chunk partial sums for BN stats, coalesced reads.
__global__ __launch_bounds__(192) void k_bnA(
        const float* __restrict__ flat, float* __restrict__ psum,
        float* __restrict__ psq) {
    const int f = threadIdx.x;
    if (f >= NF) return;
    const int p = blockIdx.x;
    const float* base = flat + (size_t)p * 64 * NF + f;
    float s0 = 0.0f, s1 = 0.0f, q0 = 0.0f, q1 = 0.0f;
    #pragma unroll 4
    for (int r = 0; r < 64; r += 2) {
        float a = base[(size_t)r * NF];
        float b2 = base[(size_t)(r + 1) * NF];
        s0 += a; q0 += a * a;
        s1 += b2; q1 += b2 * b2;
    }
    psum[p * NF + f] = s0 + s1;
    psq[p * NF + f] = q0 + q1;
}

// K3b: reduce partials -> fused scale/shift.
__global__ __launch_bounds__(256) void k_bnB(
        const float* __restrict__ psum, const float* __restrict__ psq,
        const float* __restrict__ gamma, const float* __restrict__ beta,
        float* __restrict__ scale, float* __restrict__ shift) {
    const int f = blockIdx.x;
    const int p = threadIdx.x;
    float s = psum[p * NF + f];
    float q = psq[p * NF + f];
    #pragma unroll
    for (int o = 32; o > 0; o >>= 1) {
        s += __shfl_down(s, o, 64);
        q += __shfl_down(q, o, 64);
    }
    __shared__ float rs[4], rq[4];
    const int wv = p >> 6;
    if ((p & 63) == 0) { rs[wv] = s; rq[wv] = q; }
    __syncthreads();
    if (p == 0) {
        float S = rs[0] + rs[1] + rs[2] + rs[3];
        float Q = rq[0] + rq[1] + rq[2] + rq[3];
        float mean = S * (1.0f / NB);
        float var = Q * (1.0f / NB) - mean * mean;
        float sc = gamma[f] * rsqrtf(var + 1e-5f);
        scale[f] = sc;
        shift[f] = beta[f] - mean * sc;
    }
}

// K4: BN-apply + LeakyReLU + concat + FC(162->2) + softmax.
__global__ __launch_bounds__(256) void k_fc(
        const float* __restrict__ flat, const float* __restrict__ scale,
        const float* __restrict__ shift, const float* __restrict__ ag,
        const float* __restrict__ fcw, const float* __restrict__ fcb,
        float* __restrict__ out) {
    const int lane = threadIdx.x & 63;
    const int b = blockIdx.x * 4 + (threadIdx.x >> 6);
    const float* fr = flat + (size_t)b * NF;
    float p0 = 0.0f, p1 = 0.0f;
    for (int f = lane; f < NF; f += 64) {
        float xn = fr[f] * scale[f] + shift[f];
        float a = xn >= 0.0f ? xn : 0.01f * xn;
        p0 += a * fcw[f];
        p1 += a * fcw[162 + f];
    }
    #pragma unroll
    for (int o = 32; o > 0; o >>= 1) {
        p0 += __shfl_down(p0, o, 64);
        p1 += __shfl_down(p1, o, 64);
    }
    if (lane == 0) {
        float a0 = ag[(size_t)b * 2 + 0], a1 = ag[(size_t)b * 2 + 1];
        float l0 = p0 + a0 * fcw[160] + a1 * fcw[161] + fcb[0];
        float l1 = p1 + a0 * fcw[162 + 160] + a1 * fcw[162 + 161] + fcb[1];
        float m = fmaxf(l0, l1);
        float e0 = __expf(l0 - m), e1 = __expf(l1 - m);
        float inv = 1.0f / (e0 + e1);
        out[(size_t)b * 2 + 0] = e0 * inv;
        out[(size_t)b * 2 + 1] = e1 * inv;
    }
}

extern "C" void kernel_launch(void* const* d_in, const int* in_sizes, int n_in,
                              void* d_out, int out_size, void* d_ws, size_t ws_size,
                              hipStream_t stream) {
    const float* x     = (const float*)d_in[0];
    const float* ag    = (const float*)d_in[1];
    const float* wih0  = (const float*)d_in[2];
    const float* whh0  = (const float*)d_in[3];
    const float* bih0  = (const float*)d_in[4];
    const float* bhh0  = (const float*)d_in[5];
    const float* wih1  = (const float*)d_in[6];
    const float* whh1  = (const float*)d_in[7];
    const float* bih1  = (const float*)d_in[8];
    const float* bhh1  = (const float*)d_in[9];
    const float* gamma = (const float*)d_in[10];
    const float* beta  = (const float*)d_in[11];
    const float* fcw   = (const float*)d_in[12];
    const float* fcb   = (const float*)d_in[13];
    float* out = (float*)d_out;

    float* ws = (float*)d_ws;
    float* xgF   = ws;                       // 10,485,760 floats (frag layout)
    float* flat  = ws + 10485760;            //  2,621,440 floats
    float* psum  = ws + 13107200;            //     40,960 floats (256*160)
    float* psq   = ws + 13148160;            //     40,960 floats
    float* scale = ws + 13189120;            //        160
    float* shift = ws + 13189280;            //        160
    half8* Bf    = (half8*)(ws + 13189440);  //      8,192 floats (32 KB)
    float* bsum  = ws + 13197632;            //         64

    k_prep<<<dim3(8),    dim3(256), 0, stream>>>(wih0, bih0, bhh0, Bf, bsum);
    k_proj<<<dim3(2560), dim3(256), 0, stream>>>(x, Bf, bsum, xgF);
    k_lstm<<<dim3(4096), dim3(256), 0, stream>>>(xgF, whh0, wih1, whh1, bih1, bhh1, flat);
    k_bnA<<<dim3(256),  dim3(192), 0, stream>>>(flat, psum, psq);
    k_bnB<<<dim3(160),  dim3(256), 0, stream>>>(psum, psq, gamma, beta, scale, shift);
    k_fc<<<dim3(4096),  dim3(256), 0, stream>>>(flat, scale, shift, ag, fcw, fcb, out);
}